// Round 16
// baseline (84.214 us; speedup 1.0000x reference)
//
#include <hip/hip_runtime.h>

// Problem constants (match reference)
#define NB 32768
#define ND 512
#define NK 10

#define LEFTB (-10.0f)
#define RIGHTB (10.0f)
#define ROWS 8
#define NBLK 512                      // blocks of 1024 threads; 2 blocks/CU
#define SWEEPS (NB / (NBLK * 16))     // = 4 (16 rows per block per sweep)

typedef __attribute__((ext_vector_type(2))) float f32x2;

__device__ __forceinline__ float rcpf1(float v) { return __builtin_amdgcn_rcpf(v); }

// ---------------------------------------------------------------------------
// Workspace layout (floats):
//   E     [ 9][512]          internal knots cw[1..9] (register bin search)
//   GCWCH [11][512] float2   {cw_k, ch_k} knot pairs
//   GDD   [11][512]          d_k
// ---------------------------------------------------------------------------
#define OFF_CWCH (9 * ND)                   // floats
#define OFF_DD   (OFF_CWCH + 22 * ND)       // floats

__global__ void rqs_precompute(const float* __restrict__ uw,
                               const float* __restrict__ uh,
                               const float* __restrict__ ud,
                               float* __restrict__ ws) {
    int f = blockIdx.x * blockDim.x + threadIdx.x;
    if (f >= ND) return;

    float* E = ws;
    float2* GCWCH = (float2*)(ws + OFF_CWCH);
    float* GDD = ws + OFF_DD;

    float cw[NK + 1], ch[NK + 1], dd[NK + 1];

    // ---- widths -> x-knots ----
    {
        float u[NK];
        float m = -1e30f;
#pragma unroll
        for (int k = 0; k < NK; ++k) { u[k] = uw[f * NK + k]; m = fmaxf(m, u[k]); }
        float s = 0.0f;
#pragma unroll
        for (int k = 0; k < NK; ++k) { u[k] = expf(u[k] - m); s += u[k]; }
        float inv = 1.0f / s;
        float c = 0.0f;
        cw[0] = LEFTB;
#pragma unroll
        for (int k = 0; k < NK; ++k) {
            c += 1e-3f + (1.0f - 1e-3f * NK) * (u[k] * inv);
            cw[k + 1] = (RIGHTB - LEFTB) * c + LEFTB;
        }
        cw[NK] = RIGHTB;
    }
    // ---- heights -> y-knots ----
    {
        float u[NK];
        float m = -1e30f;
#pragma unroll
        for (int k = 0; k < NK; ++k) { u[k] = uh[f * NK + k]; m = fmaxf(m, u[k]); }
        float s = 0.0f;
#pragma unroll
        for (int k = 0; k < NK; ++k) { u[k] = expf(u[k] - m); s += u[k]; }
        float inv = 1.0f / s;
        float c = 0.0f;
        ch[0] = LEFTB;
#pragma unroll
        for (int k = 0; k < NK; ++k) {
            c += 1e-3f + (1.0f - 1e-3f * NK) * (u[k] * inv);
            ch[k + 1] = (RIGHTB - LEFTB) * c + LEFTB;
        }
        ch[NK] = RIGHTB;
    }
    // ---- derivatives: boundary pads are exactly 1.0 ----
    dd[0] = 1.0f;
    dd[NK] = 1.0f;
#pragma unroll
    for (int k = 1; k < NK; ++k) {
        float v = ud[f * (NK - 1) + (k - 1)];
        dd[k] = 1e-3f + fmaxf(v, 0.0f) + log1pf(expf(-fabsf(v)));
    }

    // ---- store ----
#pragma unroll
    for (int j = 0; j < 9; ++j) E[j * ND + f] = cw[j + 1];
#pragma unroll
    for (int k = 0; k <= NK; ++k) {
        GCWCH[k * ND + f] = make_float2(cw[k], ch[k]);
        GDD[k * ND + f] = dd[k];
    }
}

// DPP row_shr:N add (VALU-only partial reduction within 16-lane rows).
__device__ __forceinline__ float dpp_row_reduce16(float v) {
    v += __int_as_float(__builtin_amdgcn_update_dpp(
        0, __float_as_int(v), 0x111, 0xF, 0xF, true));  // row_shr:1
    v += __int_as_float(__builtin_amdgcn_update_dpp(
        0, __float_as_int(v), 0x112, 0xF, 0xF, true));  // row_shr:2
    v += __int_as_float(__builtin_amdgcn_update_dpp(
        0, __float_as_int(v), 0x114, 0xF, 0xF, true));  // row_shr:4
    v += __int_as_float(__builtin_amdgcn_update_dpp(
        0, __float_as_int(v), 0x118, 0xF, 0xF, true));  // row_shr:8
    return v;
}

// ---------------------------------------------------------------------------
// Main transform (round-14 structure). 1024 threads/block (feature = t&511,
// row-half = t>>9), 512 blocks -> 2 blocks/CU = 32 waves/CU, VGPR capped 64.
// NEW: spline math is element-PAIRED into ext_vector float2 so the compiler
// emits VOP3P v_pk_{fma,mul,add}_f32 — testing whether packed f32 halves the
// VALU issue cost of the ~30 packable ops/elem. Bin search, LDS gathers,
// rcp/log2 and selects stay scalar (not packable).
// ---------------------------------------------------------------------------
__global__ __launch_bounds__(1024, 8) void rqs_main(const float* __restrict__ X,
                                                    const float* __restrict__ ws,
                                                    float* __restrict__ Y,
                                                    float* __restrict__ logdet) {
    const int t = threadIdx.x;
    const int fl = t & (ND - 1);   // feature
    const int hf = t >> 9;         // row-half 0/1

    __shared__ float2 sCWCH[NK + 1][ND];  // 45056 B
    __shared__ float sDD[NK + 1][ND];     // 22528 B
    __shared__ float sPart[SWEEPS * 16][32] __attribute__((aligned(16)));  // 8192 B
    // total 75776 B -> 2 blocks/CU

    const float* E = ws;
    const float2* GCWCH = (const float2*)(ws + OFF_CWCH);
    const float* GDD = ws + OFF_DD;

    // issue sweep-0 X loads FIRST (independent of table staging)
    float xs[ROWS];
    {
        const int rb = blockIdx.x * 16 + hf * ROWS;
#pragma unroll
        for (int i = 0; i < ROWS; ++i)
            xs[i] = __builtin_nontemporal_load(&X[(rb + i) * ND + fl]);
    }

    // halves split the table staging
    if (hf == 0) {
#pragma unroll
        for (int k = 0; k <= NK; ++k) sCWCH[k][fl] = GCWCH[k * ND + fl];
    } else {
#pragma unroll
        for (int k = 0; k <= NK; ++k) sDD[k][fl] = GDD[k * ND + fl];
    }
    float e[9];
#pragma unroll
    for (int j = 0; j < 9; ++j) e[j] = E[j * ND + fl];
    __syncthreads();

    const f32x2 n2 = {-2.0f, -2.0f};

#pragma unroll
    for (int it = 0; it < SWEEPS; ++it) {
        const int rb = blockIdx.x * 16 + it * (NBLK * 16) + hf * ROWS;

        // prefetch next sweep's X during this sweep's compute
        float xn[ROWS];
        if (it + 1 < SWEEPS) {
            const int rn = rb + NBLK * 16;
#pragma unroll
            for (int i = 0; i < ROWS; ++i)
                xn[i] = __builtin_nontemporal_load(&X[(rn + i) * ND + fl]);
        }

        float ys[ROWS], ls[ROWS];
#pragma unroll
        for (int p = 0; p < ROWS / 2; ++p) {
            const int i0 = 2 * p, i1 = 2 * p + 1;
            const float xa = xs[i0], xb = xs[i1];

            // scalar bin searches (saturate outside, same as clamp)
            int ia = 0, ib = 0;
#pragma unroll
            for (int j = 0; j < 9; ++j) {
                ia += (xa >= e[j]) ? 1 : 0;
                ib += (xb >= e[j]) ? 1 : 0;
            }

            // scalar gathers (conflict-free layout)
            const float2 c0a = sCWCH[ia][fl], c1a = sCWCH[ia + 1][fl];
            const float2 c0b = sCWCH[ib][fl], c1b = sCWCH[ib + 1][fl];
            const f32x2 dk  = {sDD[ia][fl], sDD[ib][fl]};
            const f32x2 dk1 = {sDD[ia + 1][fl], sDD[ib + 1][fl]};

            // packed math on the element pair
            const f32x2 x2  = {xa, xb};
            const f32x2 cw  = {c0a.x, c0b.x};
            const f32x2 ch  = {c0a.y, c0b.y};
            const f32x2 cw1 = {c1a.x, c1b.x};
            const f32x2 ch1 = {c1a.y, c1b.y};

            f32x2 w = cw1 - cw;
            f32x2 rw = {rcpf1(w.x), rcpf1(w.y)};       // w >= 0.02 always
            f32x2 h = ch1 - ch;
            f32x2 delta = h * rw;

            f32x2 theta = (x2 - cw) * rw;
            f32x2 omt = 1.0f - theta;
            f32x2 t1m = theta * omt;
            f32x2 th2 = theta * theta;

            f32x2 num = h * __builtin_elementwise_fma(delta, th2, dk * t1m);
            f32x2 den = __builtin_elementwise_fma(
                __builtin_elementwise_fma(n2, delta, dk + dk1), t1m, delta);
            f32x2 rden = {rcpf1(den.x), rcpf1(den.y)};  // den > 0 inside
            f32x2 y2 = __builtin_elementwise_fma(num, rden, ch);

            f32x2 tt = __builtin_elementwise_fma(dk1, th2, (delta + delta) * t1m);
            f32x2 dnum = (delta * delta) *
                         __builtin_elementwise_fma(dk, omt * omt, tt);
            f32x2 arg = dnum * rden * rden;

            float lada = __log2f(arg.x);                // log2; ln2 at epilogue
            float ladb = __log2f(arg.y);

            bool ina = fabsf(xa) <= RIGHTB;             // abs = free src modifier
            bool inb = fabsf(xb) <= RIGHTB;
            ys[i0] = ina ? y2.x : xa;
            ys[i1] = inb ? y2.y : xb;
            ls[i0] = ina ? lada : 0.0f;
            ls[i1] = inb ? ladb : 0.0f;
        }

#pragma unroll
        for (int i = 0; i < ROWS; ++i)
            __builtin_nontemporal_store(ys[i], &Y[(rb + i) * ND + fl]);

        // pure-VALU DPP reduce within 16-lane groups; lane 15 holds group sum
#pragma unroll
        for (int i = 0; i < ROWS; ++i) ls[i] = dpp_row_reduce16(ls[i]);
        if ((t & 15) == 15) {
            int g = fl >> 4;  // 0..31
#pragma unroll
            for (int i = 0; i < ROWS; ++i)
                sPart[it * 16 + hf * ROWS + i][g] = ls[i];
        }
        // no barrier: each sweep writes a distinct sPart region

        if (it + 1 < SWEEPS) {
#pragma unroll
            for (int i = 0; i < ROWS; ++i) xs[i] = xn[i];
        }
    }

    // ---- epilogue: finish all 64 rows' logdet in one pass ----
    __syncthreads();
    {
        const int rl = t >> 4;              // local row 0..63
        const int c = t & 15;               // 16 threads per row
        const int it = rl >> 4;             // sweep
        const int rem = rl & 15;            // row within sweep (incl. half)
        float2 v2 = *(const float2*)&sPart[rl][c * 2];
        float v = v2.x + v2.y;
        v += __shfl_xor(v, 1, 16);
        v += __shfl_xor(v, 2, 16);
        v += __shfl_xor(v, 4, 16);
        v += __shfl_xor(v, 8, 16);
        if (c == 0) {
            const int row = blockIdx.x * 16 + it * (NBLK * 16) + rem;
            logdet[row] = v * 0.6931471805599453f;
        }
    }
}

extern "C" void kernel_launch(void* const* d_in, const int* in_sizes, int n_in,
                              void* d_out, int out_size, void* d_ws, size_t ws_size,
                              hipStream_t stream) {
    const float* x  = (const float*)d_in[0];
    const float* uw = (const float*)d_in[1];
    const float* uh = (const float*)d_in[2];
    const float* ud = (const float*)d_in[3];

    float* out = (float*)d_out;
    float* Y = out;                              // [NB*ND]
    float* logdet = out + (size_t)NB * ND;       // [NB]

    float* ws = (float*)d_ws;                    // tables: 53*512 floats (~106 KB)

    hipLaunchKernelGGL(rqs_precompute, dim3(4), dim3(128), 0, stream,
                       uw, uh, ud, ws);
    hipLaunchKernelGGL(rqs_main, dim3(NBLK), dim3(1024), 0, stream,
                       x, ws, Y, logdet);
}

// Round 17
// 40.997 us; speedup vs baseline: 2.0541x; 2.0541x over previous
//
#include <hip/hip_runtime.h>

// Problem constants (match reference)
#define NB 32768
#define ND 512
#define NK 10

#define LEFTB (-10.0f)
#define RIGHTB (10.0f)
#define ROWS 8
#define NBLK 512                      // blocks of 1024 threads; 2 blocks/CU
#define SWEEPS (NB / (NBLK * 16))     // = 4 (16 rows per block per sweep)

// ---------------------------------------------------------------------------
// Workspace layout (floats):
//   E     [ 9][512]          internal knots cw[1..9] (register bin search)
//   GCWCH [11][512] float2   {cw_k, ch_k} knot pairs
//   GDD   [11][512]          d_k
// ---------------------------------------------------------------------------
#define OFF_CWCH (9 * ND)                   // floats
#define OFF_DD   (OFF_CWCH + 22 * ND)       // floats

__global__ void rqs_precompute(const float* __restrict__ uw,
                               const float* __restrict__ uh,
                               const float* __restrict__ ud,
                               float* __restrict__ ws) {
    int f = blockIdx.x * blockDim.x + threadIdx.x;
    if (f >= ND) return;

    float* E = ws;
    float2* GCWCH = (float2*)(ws + OFF_CWCH);
    float* GDD = ws + OFF_DD;

    float cw[NK + 1], ch[NK + 1], dd[NK + 1];

    // ---- widths -> x-knots ----
    {
        float u[NK];
        float m = -1e30f;
#pragma unroll
        for (int k = 0; k < NK; ++k) { u[k] = uw[f * NK + k]; m = fmaxf(m, u[k]); }
        float s = 0.0f;
#pragma unroll
        for (int k = 0; k < NK; ++k) { u[k] = expf(u[k] - m); s += u[k]; }
        float inv = 1.0f / s;
        float c = 0.0f;
        cw[0] = LEFTB;
#pragma unroll
        for (int k = 0; k < NK; ++k) {
            c += 1e-3f + (1.0f - 1e-3f * NK) * (u[k] * inv);
            cw[k + 1] = (RIGHTB - LEFTB) * c + LEFTB;
        }
        cw[NK] = RIGHTB;
    }
    // ---- heights -> y-knots ----
    {
        float u[NK];
        float m = -1e30f;
#pragma unroll
        for (int k = 0; k < NK; ++k) { u[k] = uh[f * NK + k]; m = fmaxf(m, u[k]); }
        float s = 0.0f;
#pragma unroll
        for (int k = 0; k < NK; ++k) { u[k] = expf(u[k] - m); s += u[k]; }
        float inv = 1.0f / s;
        float c = 0.0f;
        ch[0] = LEFTB;
#pragma unroll
        for (int k = 0; k < NK; ++k) {
            c += 1e-3f + (1.0f - 1e-3f * NK) * (u[k] * inv);
            ch[k + 1] = (RIGHTB - LEFTB) * c + LEFTB;
        }
        ch[NK] = RIGHTB;
    }
    // ---- derivatives: boundary pads are exactly 1.0 ----
    dd[0] = 1.0f;
    dd[NK] = 1.0f;
#pragma unroll
    for (int k = 1; k < NK; ++k) {
        float v = ud[f * (NK - 1) + (k - 1)];
        dd[k] = 1e-3f + fmaxf(v, 0.0f) + log1pf(expf(-fabsf(v)));
    }

    // ---- store ----
#pragma unroll
    for (int j = 0; j < 9; ++j) E[j * ND + f] = cw[j + 1];
#pragma unroll
    for (int k = 0; k <= NK; ++k) {
        GCWCH[k * ND + f] = make_float2(cw[k], ch[k]);
        GDD[k * ND + f] = dd[k];
    }
}

// DPP row_shr:N add (VALU-only partial reduction within 16-lane rows).
__device__ __forceinline__ float dpp_row_reduce16(float v) {
    v += __int_as_float(__builtin_amdgcn_update_dpp(
        0, __float_as_int(v), 0x111, 0xF, 0xF, true));  // row_shr:1
    v += __int_as_float(__builtin_amdgcn_update_dpp(
        0, __float_as_int(v), 0x112, 0xF, 0xF, true));  // row_shr:2
    v += __int_as_float(__builtin_amdgcn_update_dpp(
        0, __float_as_int(v), 0x114, 0xF, 0xF, true));  // row_shr:4
    v += __int_as_float(__builtin_amdgcn_update_dpp(
        0, __float_as_int(v), 0x118, 0xF, 0xF, true));  // row_shr:8
    return v;
}

// ---------------------------------------------------------------------------
// Main transform (round-14 configuration — empirical optimum).
// 1024 threads/block (feature = t&511, row-half = t>>9), 512 blocks ->
// 2 blocks/CU = 32 waves/CU; VGPR capped at 64 by launch bounds. Batched
// body (8 elements' gathers pipeline); barrier-free sweeps (private sPart
// region per sweep); pure-VALU DPP reduce in log2 units; in-kernel logdet
// epilogue. LDS [knot][512] planes: stride == 0 mod 32 banks -> per-lane
// idx gather is conflict-free.
// ---------------------------------------------------------------------------
__global__ __launch_bounds__(1024, 8) void rqs_main(const float* __restrict__ X,
                                                    const float* __restrict__ ws,
                                                    float* __restrict__ Y,
                                                    float* __restrict__ logdet) {
    const int t = threadIdx.x;
    const int fl = t & (ND - 1);   // feature
    const int hf = t >> 9;         // row-half 0/1

    __shared__ float2 sCWCH[NK + 1][ND];  // 45056 B
    __shared__ float sDD[NK + 1][ND];     // 22528 B
    __shared__ float sPart[SWEEPS * 16][32] __attribute__((aligned(16)));  // 8192 B
    // total 75776 B -> 2 blocks/CU

    const float* E = ws;
    const float2* GCWCH = (const float2*)(ws + OFF_CWCH);
    const float* GDD = ws + OFF_DD;

    // issue sweep-0 X loads FIRST (independent of precompute output)
    float xs[ROWS];
    {
        const int rb = blockIdx.x * 16 + hf * ROWS;
#pragma unroll
        for (int i = 0; i < ROWS; ++i)
            xs[i] = __builtin_nontemporal_load(&X[(rb + i) * ND + fl]);
    }

    // halves split the table staging
    if (hf == 0) {
#pragma unroll
        for (int k = 0; k <= NK; ++k) sCWCH[k][fl] = GCWCH[k * ND + fl];
    } else {
#pragma unroll
        for (int k = 0; k <= NK; ++k) sDD[k][fl] = GDD[k * ND + fl];
    }
    float e[9];
#pragma unroll
    for (int j = 0; j < 9; ++j) e[j] = E[j * ND + fl];
    __syncthreads();

    for (int it = 0; it < SWEEPS; ++it) {
        const int rb = blockIdx.x * 16 + it * (NBLK * 16) + hf * ROWS;

        // prefetch next sweep's X during this sweep's compute
        float xn[ROWS];
        if (it + 1 < SWEEPS) {
            const int rn = rb + NBLK * 16;
#pragma unroll
            for (int i = 0; i < ROWS; ++i)
                xn[i] = __builtin_nontemporal_load(&X[(rn + i) * ND + fl]);
        }

        float ys[ROWS], ls[ROWS];
#pragma unroll
        for (int i = 0; i < ROWS; ++i) {
            float x = xs[i];

            // bin search on raw x: saturates to 0 / 9 outside, same as clamp
            int idx = 0;
#pragma unroll
            for (int j = 0; j < 9; ++j) idx += (x >= e[j]) ? 1 : 0;

            float2 c0 = sCWCH[idx][fl];      // {cw_k,   ch_k}
            float2 c1 = sCWCH[idx + 1][fl];  // {cw_k+1, ch_k+1}
            float dk = sDD[idx][fl];
            float dk1 = sDD[idx + 1][fl];

            float w = c1.x - c0.x;
            float rw = __builtin_amdgcn_rcpf(w);   // w >= 0.02 always
            float h = c1.y - c0.y;
            float delta = h * rw;

            float theta = (x - c0.x) * rw;
            float omt = 1.0f - theta;
            float t1m = theta * omt;
            float th2 = theta * theta;

            float num = h * fmaf(delta, th2, dk * t1m);
            float den = fmaf(fmaf(-2.0f, delta, dk + dk1), t1m, delta);
            float rden = __builtin_amdgcn_rcpf(den);  // den > 0 inside
            float y = fmaf(num, rden, c0.y);

            float dnum = delta * delta *
                         (fmaf(dk1, th2, 2.0f * delta * t1m) + dk * omt * omt);
            float lad2 = __log2f(dnum * rden * rden);  // log2; ln2 at epilogue

            bool inside = fabsf(x) <= RIGHTB;          // abs = free src modifier
            ys[i] = inside ? y : x;
            ls[i] = inside ? lad2 : 0.0f;
        }

#pragma unroll
        for (int i = 0; i < ROWS; ++i)
            __builtin_nontemporal_store(ys[i], &Y[(rb + i) * ND + fl]);

        // pure-VALU DPP reduce within 16-lane groups; lane 15 holds group sum
#pragma unroll
        for (int i = 0; i < ROWS; ++i) ls[i] = dpp_row_reduce16(ls[i]);
        if ((t & 15) == 15) {
            int g = fl >> 4;  // 0..31
#pragma unroll
            for (int i = 0; i < ROWS; ++i)
                sPart[it * 16 + hf * ROWS + i][g] = ls[i];
        }
        // no barrier: each sweep writes a distinct sPart region

#pragma unroll
        for (int i = 0; i < ROWS; ++i) xs[i] = xn[i];
    }

    // ---- epilogue: finish all 64 rows' logdet in one pass ----
    __syncthreads();
    {
        const int rl = t >> 4;              // local row 0..63
        const int c = t & 15;               // 16 threads per row
        const int it = rl >> 4;             // sweep
        const int rem = rl & 15;            // row within sweep (incl. half)
        float2 v2 = *(const float2*)&sPart[rl][c * 2];
        float v = v2.x + v2.y;
        v += __shfl_xor(v, 1, 16);
        v += __shfl_xor(v, 2, 16);
        v += __shfl_xor(v, 4, 16);
        v += __shfl_xor(v, 8, 16);
        if (c == 0) {
            const int row = blockIdx.x * 16 + it * (NBLK * 16) + rem;
            logdet[row] = v * 0.6931471805599453f;
        }
    }
}

extern "C" void kernel_launch(void* const* d_in, const int* in_sizes, int n_in,
                              void* d_out, int out_size, void* d_ws, size_t ws_size,
                              hipStream_t stream) {
    const float* x  = (const float*)d_in[0];
    const float* uw = (const float*)d_in[1];
    const float* uh = (const float*)d_in[2];
    const float* ud = (const float*)d_in[3];

    float* out = (float*)d_out;
    float* Y = out;                              // [NB*ND]
    float* logdet = out + (size_t)NB * ND;       // [NB]

    float* ws = (float*)d_ws;                    // tables: 53*512 floats (~106 KB)

    hipLaunchKernelGGL(rqs_precompute, dim3(4), dim3(128), 0, stream,
                       uw, uh, ud, ws);
    hipLaunchKernelGGL(rqs_main, dim3(NBLK), dim3(1024), 0, stream,
                       x, ws, Y, logdet);
}